// Round 6
// baseline (11357.880 us; speedup 1.0000x reference)
//
#include <hip/hip_runtime.h>
#include <hip/hip_fp16.h>

typedef _Float16 half8 __attribute__((ext_vector_type(8)));
typedef float f32x4 __attribute__((ext_vector_type(4)));

#define T_STEPS 512

static __device__ __forceinline__ float sigf(float x) {
    return __builtin_amdgcn_rcpf(1.0f + __builtin_amdgcn_exp2f(-1.44269504088896f * x));
}
static __device__ __forceinline__ float tanhf_fast(float x) {
    return 2.0f * __builtin_amdgcn_rcpf(1.0f + __builtin_amdgcn_exp2f(-2.88539008177793f * x)) - 1.0f;
}

// Persistent LSTM v6: hybrid sync (MALL flags + local-L2 data), all-wave poll,
// LDS-epoch barriers with VALU busywork (DPM clock gamble), b128 staging.
// s = XCC_ID, jj = rank within XCD. 1 WG/CU via ~83KB LDS -> 32 WGs/XCD.
// Producer: plain data stores (write-through -> local L2) -> vmcnt(0) ->
//           agent-atomic flag store (MALL).  Consumer: relaxed agent poll
//           (MALL, no fence in loop) -> ONE acquire fence (L1 inv; L2 dirty
//           lines intact) -> plain staging loads (local L2 hits).
__global__ __launch_bounds__(512, 2) void lstm_persist(
    const float* __restrict__ y_hist,  // [128][512]
    const float* __restrict__ W_ih,    // [4096]
    const float* __restrict__ W_hh,    // [4096][1024]
    const float* __restrict__ b_ih,    // [4096]
    const float* __restrict__ b_hh,    // [4096]
    const float* __restrict__ fc_W,    // [128][1024]
    const float* __restrict__ fc_b,    // [128]
    const float* __restrict__ h0,      // [128][1024]
    const float* __restrict__ c0,      // [128][1024]
    float* __restrict__ out,           // [128][128]
    unsigned long long* __restrict__ hbuf0,  // [8][4096] u64 = [grp][jjp][n][u] fp16
    unsigned long long* __restrict__ hbuf1,
    float* __restrict__ hfin,                // fp32 h_T [128][1024]
    unsigned int* __restrict__ flags,        // [8][32]  (MALL atomics only)
    unsigned int* __restrict__ xcnt)         // [8] rank counters (MALL atomics only)
{
    __shared__ _Float16 h_lds[16 * 1024];          // 32KB [n][k], byte^((n&7)<<4)
    __shared__ float    y_lds[512][16];            // 32KB
    __shared__ unsigned long long hout_lds[128];   // 1KB
    __shared__ unsigned sjj[2];
    __shared__ unsigned bar_ctr;

    const int tid = threadIdx.x;
    const int l   = tid & 63;
    const int wid = tid >> 6;
    const int q4  = l >> 4;
    const int n   = l & 15;

    if (tid == 0) {
        bar_ctr = 0;
        unsigned x;
        asm volatile("s_getreg_b32 %0, hwreg(HW_REG_XCC_ID)" : "=s"(x));
        x &= 7u;
        sjj[0] = x;
        sjj[1] = atomicAdd(&xcnt[x], 1u) & 31u;   // device-scope (MALL), memset-safe
    }
    __syncthreads();
    const int s  = (int)sjj[0];
    const int jj = (int)sjj[1];

    // ---- W_hh -> fp16 A-fragments (full K): k = 32c + 8*q4 + j ----
    half8 wfrag[32];
    {
        const int r16  = l & 15;
        const int u_a  = 4 * wid + (r16 >> 2);
        const int g_a  = r16 & 3;
        const int grow = g_a * 1024 + 32 * jj + u_a;
        const float* wrow = W_hh + (size_t)grow * 1024 + 8 * q4;
        #pragma unroll
        for (int c = 0; c < 32; ++c) {
            f32x4 a0 = *(const f32x4*)(wrow + 32 * c);
            f32x4 a1 = *(const f32x4*)(wrow + 32 * c + 4);
            half8 w;
            w[0]=(_Float16)a0[0]; w[1]=(_Float16)a0[1];
            w[2]=(_Float16)a0[2]; w[3]=(_Float16)a0[3];
            w[4]=(_Float16)a1[0]; w[5]=(_Float16)a1[1];
            w[6]=(_Float16)a1[2]; w[7]=(_Float16)a1[3];
            wfrag[c] = w;
        }
    }

    // ---- per-lane epilogue constants: lane owns (batch n, unit u_e = 4*wid+q4) ----
    const int u_e = 4 * wid + q4;
    float wih_r[4], bias_r[4], creg;
    #pragma unroll
    for (int g = 0; g < 4; ++g) {
        const int gr = g * 1024 + 32 * jj + u_e;
        wih_r[g]  = W_ih[gr];
        bias_r[g] = b_ih[gr] + b_hh[gr];
    }
    creg = c0[(size_t)(16 * s + n) * 1024 + 32 * jj + u_e];

    // ---- preload whole y tile (once) ----
    {
        const int r = tid >> 5, sg = tid & 31;
        const float* yr = y_hist + (size_t)(16 * s + r) * 512;
        #pragma unroll
        for (int e = 0; e < 4; ++e) {
            f32x4 v = *(const f32x4*)(yr + sg * 4 + 128 * e);
            #pragma unroll
            for (int j = 0; j < 4; ++j) y_lds[sg * 4 + 128 * e + j][r] = v[j];
        }
    }
    // ---- stage h(0) = h0 ----
    {
        const int r = tid >> 5, sg = tid & 31;
        const int swz0 = (r & 7) << 4;
        const float* hr = h0 + (size_t)(16 * s + r) * 1024 + sg * 32;
        char* db = (char*)h_lds + r * 2048;
        #pragma unroll
        for (int v = 0; v < 4; ++v) {
            f32x4 a0 = *(const f32x4*)(hr + 8 * v);
            f32x4 a1 = *(const f32x4*)(hr + 8 * v + 4);
            half8 hv;
            hv[0]=(_Float16)a0[0]; hv[1]=(_Float16)a0[1];
            hv[2]=(_Float16)a0[2]; hv[3]=(_Float16)a0[3];
            hv[4]=(_Float16)a1[0]; hv[5]=(_Float16)a1[1];
            hv[6]=(_Float16)a1[2]; hv[7]=(_Float16)a1[3];
            *(half8*)(db + ((sg * 64 + 16 * v) ^ swz0)) = hv;
        }
    }
    __syncthreads();

    const int bb  = n * 2048 + 16 * q4;   // B-frag base byte (pre-swizzle)
    const int swz = (n & 7) << 4;

    unsigned bar_tgt = 0;
    float junk = 1.0f + 1e-7f * (float)tid;

    // LDS-epoch barrier with VALU busywork while waiting (keeps SIMDs issuing).
#define WG_BARRIER() do {                                                      \
    asm volatile("s_waitcnt lgkmcnt(0)" ::: "memory");                         \
    if (l == 0)                                                                \
        __hip_atomic_fetch_add(&bar_ctr, 1u, __ATOMIC_RELAXED,                 \
                               __HIP_MEMORY_SCOPE_WORKGROUP);                  \
    bar_tgt += 8;                                                              \
    int _g = 0;                                                                \
    for (;;) {                                                                 \
        unsigned _v = __hip_atomic_load(&bar_ctr, __ATOMIC_RELAXED,            \
                                        __HIP_MEMORY_SCOPE_WORKGROUP);         \
        if (_v >= bar_tgt) break;                                              \
        if (++_g > (1 << 14)) break;                                           \
        _Pragma("unroll")                                                      \
        for (int _i = 0; _i < 8; ++_i)                                         \
            junk = __builtin_fmaf(junk, 1.0000001f, 1e-9f);                    \
    }                                                                          \
} while (0)

    for (int t = 0; t < T_STEPS; ++t) {
        if (t > 0) {
            // ---- publish h(t) (wave0): 16B/lane -> local L2; ack; MALL flag ----
            if (wid == 0) {
                unsigned long long* ob = ((t & 1) ? hbuf1 : hbuf0) + (s << 12) + (jj << 7);
                f32x4 pv = *(const f32x4*)&hout_lds[2 * l];
                *(f32x4*)(ob + 2 * l) = pv;
                asm volatile("s_waitcnt vmcnt(0)" ::: "memory");
                if (l == 0)
                    __hip_atomic_store(&flags[(s << 5) + jj], (unsigned)t,
                                       __ATOMIC_RELAXED, __HIP_MEMORY_SCOPE_AGENT);
            }
            // ---- all waves: relaxed MALL poll with busywork ----
            {
                const unsigned* fp = flags + (s << 5) + (l & 31);
                int g = 0;
                for (;;) {
                    unsigned fv = __hip_atomic_load(fp, __ATOMIC_RELAXED,
                                                    __HIP_MEMORY_SCOPE_AGENT);
                    if (__all((int)(fv >= (unsigned)t))) break;
                    if (++g > (1 << 13)) break;
                    #pragma unroll
                    for (int ii = 0; ii < 16; ++ii)
                        junk = __builtin_fmaf(junk, 1.0000001f, 1e-9f);
                }
                __builtin_amdgcn_fence(__ATOMIC_ACQUIRE, "agent");  // L1 inv once
            }
            // ---- stage own slice: 4 x b128 per lane (coalesced 1KB/wave reads) ----
            {
                const unsigned long long* gb = ((t & 1) ? hbuf1 : hbuf0) + (s << 12);
                #pragma unroll
                for (int k = 0; k < 4; ++k) {
                    const int F = (wid << 9) + (k << 7) + (l << 1);
                    f32x4 v = *(const f32x4*)(gb + F);
                    const int n2 = (F >> 3) & 15;
                    const int off = ((n2 * 2048) + ((F >> 7) << 6) + ((F & 7) << 3))
                                    ^ ((n2 & 7) << 4);
                    *(f32x4*)((char*)h_lds + off) = v;
                }
            }
        }
        WG_BARRIER();   // A: h_lds(t) fully staged

        // ---- MFMA: 16 units x 16 batches, full K=1024, 4 chains ----
        f32x4 ac0 = {0.f,0.f,0.f,0.f}, ac1 = {0.f,0.f,0.f,0.f};
        f32x4 ac2 = {0.f,0.f,0.f,0.f}, ac3 = {0.f,0.f,0.f,0.f};
        {
            const char* hb = (const char*)h_lds;
            #pragma unroll
            for (int c = 0; c < 8; ++c) {
                half8 b0 = *(const half8*)(hb + ((bb + 64 * c) ^ swz));
                half8 b1 = *(const half8*)(hb + ((bb + 64 * (c + 8)) ^ swz));
                half8 b2 = *(const half8*)(hb + ((bb + 1024 + 64 * c) ^ swz));
                half8 b3 = *(const half8*)(hb + ((bb + 1024 + 64 * (c + 8)) ^ swz));
                ac0 = __builtin_amdgcn_mfma_f32_16x16x32_f16(wfrag[c],      b0, ac0, 0, 0, 0);
                ac1 = __builtin_amdgcn_mfma_f32_16x16x32_f16(wfrag[c + 8],  b1, ac1, 0, 0, 0);
                ac2 = __builtin_amdgcn_mfma_f32_16x16x32_f16(wfrag[c + 16], b2, ac2, 0, 0, 0);
                ac3 = __builtin_amdgcn_mfma_f32_16x16x32_f16(wfrag[c + 24], b3, ac3, 0, 0, 0);
            }
        }
        // ---- epilogue: h(t+1) into hout_lds ----
        {
            const float yt = y_lds[t][n];
            float gi = (ac0[0] + ac1[0]) + (ac2[0] + ac3[0]) + yt * wih_r[0] + bias_r[0];
            float gf = (ac0[1] + ac1[1]) + (ac2[1] + ac3[1]) + yt * wih_r[1] + bias_r[1];
            float gg = (ac0[2] + ac1[2]) + (ac2[2] + ac3[2]) + yt * wih_r[2] + bias_r[2];
            float go = (ac0[3] + ac1[3]) + (ac2[3] + ac3[3]) + yt * wih_r[3] + bias_r[3];
            float cn = sigf(gf) * creg + sigf(gi) * tanhf_fast(gg);
            creg = cn;
            float hv = sigf(go) * tanhf_fast(cn);
            ((_Float16*)hout_lds)[n * 32 + u_e] = (_Float16)hv;
            if (t == T_STEPS - 1) {
                hfin[(size_t)(16 * s + n) * 1024 + 32 * jj + u_e] = hv;
                asm volatile("s_waitcnt vmcnt(0)" ::: "memory");  // hfin acked pre-barrier
            }
        }
        WG_BARRIER();   // B: hout ready; h_lds reads done
    }
    // ---- signal hfin ready (after barrier B(511): all waves' hfin acked) ----
    if (wid == 0 && l == 0)
        __hip_atomic_store(&flags[(s << 5) + jj], (unsigned)T_STEPS,
                           __ATOMIC_RELAXED, __HIP_MEMORY_SCOPE_AGENT);
    asm volatile("" :: "v"(junk));   // keep busywork alive

    // ---- final FC: WG (s, jj<16) -> batch b = 16s+jj ----
    if (jj < 16) {
        if (wid == 0) {
            const unsigned* fp = flags + (s << 5) + (l & 31);
            int g = 0;
            for (;;) {
                unsigned fv = __hip_atomic_load(fp, __ATOMIC_RELAXED,
                                                __HIP_MEMORY_SCOPE_AGENT);
                if (__all((int)(fv >= (unsigned)T_STEPS))) break;
                if (++g > (1 << 13)) break;
            }
        }
        __syncthreads();
        __builtin_amdgcn_fence(__ATOMIC_ACQUIRE, "agent");  // every wave: L1 clean
        float* hT  = (float*)h_lds;       // 4KB
        float* red = hT + 1024;           // 2KB
        const int b = 16 * s + jj;
        if (tid < 256) {
            f32x4 v = *(const f32x4*)(hfin + (size_t)b * 1024 + tid * 4);
            *(f32x4*)(hT + tid * 4) = v;
        }
        __syncthreads();
        {
            const int o = tid & 127, kq = tid >> 7;
            const float* wr = fc_W + (size_t)o * 1024 + kq * 256;
            const float* hp = hT + kq * 256;
            float p = 0.0f;
            #pragma unroll 8
            for (int i = 0; i < 256; i += 4) {
                f32x4 a = *(const f32x4*)(hp + i);
                f32x4 w = *(const f32x4*)(wr + i);
                p += a[0]*w[0] + a[1]*w[1] + a[2]*w[2] + a[3]*w[3];
            }
            red[kq * 128 + o] = p;
        }
        __syncthreads();
        if (tid < 128) {
            out[(size_t)b * 128 + tid] =
                red[tid] + red[128 + tid] + red[256 + tid] + red[384 + tid] + fc_b[tid];
        }
    }
}

extern "C" void kernel_launch(void* const* d_in, const int* in_sizes, int n_in,
                              void* d_out, int out_size, void* d_ws, size_t ws_size,
                              hipStream_t stream) {
    (void)in_sizes; (void)n_in; (void)out_size; (void)ws_size;
    const float* y_hist = (const float*)d_in[0];
    const float* W_ih   = (const float*)d_in[1];
    const float* W_hh   = (const float*)d_in[2];
    const float* b_ih   = (const float*)d_in[3];
    const float* b_hh   = (const float*)d_in[4];
    const float* fc_W   = (const float*)d_in[5];
    const float* fc_b   = (const float*)d_in[6];
    const float* h0     = (const float*)d_in[7];
    const float* c0     = (const float*)d_in[8];

    // d_ws: hbuf0 (256KB) | hbuf1 (256KB) | hfin (512KB) | flags (1KB) | xcnt (128B)
    char* ws = (char*)d_ws;
    unsigned long long* hbuf0 = (unsigned long long*)ws;
    unsigned long long* hbuf1 = (unsigned long long*)(ws + (256 << 10));
    float*    hfin  = (float*)(ws + (512 << 10));
    unsigned int* flags = (unsigned int*)(ws + (1024 << 10));
    unsigned int* xcnt  = (unsigned int*)(ws + (1024 << 10) + 1024);

    // flags & xcnt live at MALL (agent-scope atomics only) -> SDMA memset is safe.
    hipMemsetAsync(ws + (1024 << 10), 0, 2048, stream);
    // 16KB dynamic LDS pad -> ~83KB/WG -> 1 WG/CU -> 32 WGs per XCD.
    hipLaunchKernelGGL(lstm_persist, dim3(256), dim3(512), 16384, stream,
                       y_hist, W_ih, W_hh, b_ih, b_hh, fc_W, fc_b, h0, c0,
                       (float*)d_out, hbuf0, hbuf1, hfin, flags, xcnt);
}

// Round 8
// 2305.626 us; speedup vs baseline: 4.9262x; 4.9262x over previous
//
#include <hip/hip_runtime.h>
#include <hip/hip_fp16.h>

typedef _Float16 half8 __attribute__((ext_vector_type(8)));
typedef float f32x4 __attribute__((ext_vector_type(4)));

#define T_STEPS 512

static __device__ __forceinline__ float sigf(float x) {
    return __builtin_amdgcn_rcpf(1.0f + __builtin_amdgcn_exp2f(-1.44269504088896f * x));
}
static __device__ __forceinline__ float tanhf_fast(float x) {
    return 2.0f * __builtin_amdgcn_rcpf(1.0f + __builtin_amdgcn_exp2f(-2.88539008177793f * x)) - 1.0f;
}

// Persistent LSTM v8 = round-5 kernel (proven: 2384us, absmax 1.95e-3) with two
// targeted anti-serialization edits:
//   (1) flags strided 128B apart (one L2 line per producer WG; kills the
//       32-CU hot-line ping-pong on a single flag line),
//   (2) staging reads rotated by jj*512 u64 per WG (same coalescing; each CU
//       starts on a different 1KB chunk, kills the per-line 32-CU convoy).
// Everything else identical to round 5: XCD-local exchange (plain write-through
// stores -> local L2; volatile poll + acquire-fence per iteration), hout_lds
// transpose + wave0 coalesced publish, 3 syncthreads/step, in-kernel flag
// reset behind MALL startup barrier, fp32 hfin for the FC.
__global__ __launch_bounds__(512, 2) void lstm_persist(
    const float* __restrict__ y_hist,  // [128][512]
    const float* __restrict__ W_ih,    // [4096]
    const float* __restrict__ W_hh,    // [4096][1024]
    const float* __restrict__ b_ih,    // [4096]
    const float* __restrict__ b_hh,    // [4096]
    const float* __restrict__ fc_W,    // [128][1024]
    const float* __restrict__ fc_b,    // [128]
    const float* __restrict__ h0,      // [128][1024]
    const float* __restrict__ c0,      // [128][1024]
    float* __restrict__ out,           // [128][128]
    unsigned long long* __restrict__ hbuf0,  // [8][4096] u64 = [grp][jjp][n][u] fp16
    unsigned long long* __restrict__ hbuf1,
    float* __restrict__ hfin,                // fp32 h_T [128][1024]
    unsigned int* __restrict__ flags,        // [8][32] strided: flag(s,j) at dword ((s*32+j)*32)
    unsigned int* __restrict__ xcnt,         // [8] rank counters (MALL atomics)
    unsigned int* __restrict__ gbar)         // [8] startup barrier (MALL atomics)
{
    __shared__ _Float16 h_lds[16 * 1024];          // 32KB [n][k], byte^((n&7)<<4)
    __shared__ float    y_lds[512][16];            // 32KB
    __shared__ unsigned long long hout_lds[128];   // 1KB
    __shared__ unsigned sjj[2];

    const int tid = threadIdx.x;
    const int l   = tid & 63;
    const int wid = tid >> 6;
    const int q4  = l >> 4;
    const int n   = l & 15;

    if (tid == 0) {
        unsigned x;
        asm volatile("s_getreg_b32 %0, hwreg(HW_REG_XCC_ID)" : "=s"(x));
        x &= 7u;
        sjj[0] = x;
        sjj[1] = atomicAdd(&xcnt[x], 1u) & 31u;   // MALL, memset-safe
    }
    __syncthreads();
    const int s  = (int)sjj[0];
    const int jj = (int)sjj[1];

    // ---- in-kernel flag reset (this XCD's L2), then MALL startup barrier ----
    if (jj == 0 && tid < 32)
        *(volatile unsigned*)&flags[((s << 5) + tid) << 5] = 0u;
    asm volatile("s_waitcnt vmcnt(0)" ::: "memory");
    __syncthreads();
    if (tid == 0) {
        __hip_atomic_fetch_add(&gbar[s], 1u, __ATOMIC_RELAXED, __HIP_MEMORY_SCOPE_AGENT);
        int guard = 0;
        while (__hip_atomic_load(&gbar[s], __ATOMIC_RELAXED, __HIP_MEMORY_SCOPE_AGENT) < 32u) {
            if (++guard > (1 << 20)) break;
        }
    }
    __syncthreads();

    // ---- W_hh -> fp16 A-fragments (full K): k = 32c + 8*q4 + j ----
    half8 wfrag[32];
    {
        const int r16  = l & 15;
        const int u_a  = 4 * wid + (r16 >> 2);
        const int g_a  = r16 & 3;
        const int grow = g_a * 1024 + 32 * jj + u_a;
        const float* wrow = W_hh + (size_t)grow * 1024 + 8 * q4;
        #pragma unroll
        for (int c = 0; c < 32; ++c) {
            f32x4 a0 = *(const f32x4*)(wrow + 32 * c);
            f32x4 a1 = *(const f32x4*)(wrow + 32 * c + 4);
            half8 w;
            w[0]=(_Float16)a0[0]; w[1]=(_Float16)a0[1];
            w[2]=(_Float16)a0[2]; w[3]=(_Float16)a0[3];
            w[4]=(_Float16)a1[0]; w[5]=(_Float16)a1[1];
            w[6]=(_Float16)a1[2]; w[7]=(_Float16)a1[3];
            wfrag[c] = w;
        }
    }

    // ---- per-lane epilogue constants: lane owns (batch n, unit u_e = 4*wid+q4) ----
    const int u_e = 4 * wid + q4;
    float wih_r[4], bias_r[4], creg;
    #pragma unroll
    for (int g = 0; g < 4; ++g) {
        const int gr = g * 1024 + 32 * jj + u_e;
        wih_r[g]  = W_ih[gr];
        bias_r[g] = b_ih[gr] + b_hh[gr];
    }
    creg = c0[(size_t)(16 * s + n) * 1024 + 32 * jj + u_e];

    // ---- preload whole y tile (once) ----
    {
        const int r = tid >> 5, sg = tid & 31;
        const float* yr = y_hist + (size_t)(16 * s + r) * 512;
        #pragma unroll
        for (int e = 0; e < 4; ++e) {
            f32x4 v = *(const f32x4*)(yr + sg * 4 + 128 * e);
            #pragma unroll
            for (int j = 0; j < 4; ++j) y_lds[sg * 4 + 128 * e + j][r] = v[j];
        }
    }
    // ---- stage h(0) = h0 (immutable input) ----
    {
        const int r = tid >> 5, sg = tid & 31;
        const int swz0 = (r & 7) << 4;
        const float* hr = h0 + (size_t)(16 * s + r) * 1024 + sg * 32;
        char* db = (char*)h_lds + r * 2048;
        #pragma unroll
        for (int v = 0; v < 4; ++v) {
            f32x4 a0 = *(const f32x4*)(hr + 8 * v);
            f32x4 a1 = *(const f32x4*)(hr + 8 * v + 4);
            half8 hv;
            hv[0]=(_Float16)a0[0]; hv[1]=(_Float16)a0[1];
            hv[2]=(_Float16)a0[2]; hv[3]=(_Float16)a0[3];
            hv[4]=(_Float16)a1[0]; hv[5]=(_Float16)a1[1];
            hv[6]=(_Float16)a1[2]; hv[7]=(_Float16)a1[3];
            *(half8*)(db + ((sg * 64 + 16 * v) ^ swz0)) = hv;
        }
    }
    __syncthreads();

    const int bb  = n * 2048 + 16 * q4;   // B-frag base byte (pre-swizzle)
    const int swz = (n & 7) << 4;
    const volatile unsigned* fpoll = flags + (((s << 5) + (l & 31)) << 5);

    for (int t = 0; t < T_STEPS; ++t) {
        if (t > 0) {
            // ---- wait for h(t): volatile poll + per-iteration L1 invalidate ----
            if (wid == 0) {
                int guard = 0;
                for (;;) {
                    unsigned fv = *fpoll;
                    if (__all((int)(fv >= (unsigned)t))) break;
                    if (++guard > (1 << 15)) break;
                    __builtin_amdgcn_fence(__ATOMIC_ACQUIRE, "agent");  // waitcnt + buffer_inv
                }
                __builtin_amdgcn_fence(__ATOMIC_ACQUIRE, "agent");      // L1 clean for staging
            }
            __syncthreads();
            // ---- stage h(t): 32KB plain loads (local L2 hits), jj-rotated order ----
            const unsigned long long* gb = ((t & 1) ? hbuf1 : hbuf0) + (s << 12);
            #pragma unroll
            for (int i = 0; i < 8; ++i) {
                const int F = ((i * 512 + tid) + (jj << 9)) & 4095;   // rotate start chunk
                unsigned long long v = gb[F];
                const int n2 = (F >> 3) & 15;
                const int off = ((n2 * 2048) + ((F >> 7) << 6) + ((F & 7) << 3))
                                ^ ((n2 & 7) << 4);
                *(unsigned long long*)((char*)h_lds + off) = v;
            }
            __syncthreads();
        }

        // ---- MFMA: 16 units x 16 batches, full K=1024, 4 independent chains ----
        f32x4 ac0 = {0.f,0.f,0.f,0.f}, ac1 = {0.f,0.f,0.f,0.f};
        f32x4 ac2 = {0.f,0.f,0.f,0.f}, ac3 = {0.f,0.f,0.f,0.f};
        {
            const char* hb = (const char*)h_lds;
            #pragma unroll
            for (int c = 0; c < 8; ++c) {
                half8 b0 = *(const half8*)(hb + ((bb + 64 * c) ^ swz));
                half8 b1 = *(const half8*)(hb + ((bb + 64 * (c + 8)) ^ swz));
                half8 b2 = *(const half8*)(hb + ((bb + 1024 + 64 * c) ^ swz));
                half8 b3 = *(const half8*)(hb + ((bb + 1024 + 64 * (c + 8)) ^ swz));
                ac0 = __builtin_amdgcn_mfma_f32_16x16x32_f16(wfrag[c],      b0, ac0, 0, 0, 0);
                ac1 = __builtin_amdgcn_mfma_f32_16x16x32_f16(wfrag[c + 8],  b1, ac1, 0, 0, 0);
                ac2 = __builtin_amdgcn_mfma_f32_16x16x32_f16(wfrag[c + 16], b2, ac2, 0, 0, 0);
                ac3 = __builtin_amdgcn_mfma_f32_16x16x32_f16(wfrag[c + 24], b3, ac3, 0, 0, 0);
            }
        }
        // ---- epilogue ----
        {
            const float yt = y_lds[t][n];
            float gi = (ac0[0] + ac1[0]) + (ac2[0] + ac3[0]) + yt * wih_r[0] + bias_r[0];
            float gf = (ac0[1] + ac1[1]) + (ac2[1] + ac3[1]) + yt * wih_r[1] + bias_r[1];
            float gg = (ac0[2] + ac1[2]) + (ac2[2] + ac3[2]) + yt * wih_r[2] + bias_r[2];
            float go = (ac0[3] + ac1[3]) + (ac2[3] + ac3[3]) + yt * wih_r[3] + bias_r[3];
            float cn = sigf(gf) * creg + sigf(gi) * tanhf_fast(gg);
            creg = cn;
            float hv = sigf(go) * tanhf_fast(cn);
            ((_Float16*)hout_lds)[n * 32 + u_e] = (_Float16)hv;
            if (t == T_STEPS - 1) {
                hfin[(size_t)(16 * s + n) * 1024 + 32 * jj + u_e] = hv;  // fp32 h_T
                asm volatile("s_waitcnt vmcnt(0)" ::: "memory");  // drain before flag 512
            }
        }
        __syncthreads();
        // ---- publish h(t+1): wave0 coalesced stores (write-through) -> ack -> flag ----
        if (wid == 0) {
            unsigned long long* ob = ((t & 1) ? hbuf0 : hbuf1) + (s << 12) + (jj << 7);
            ob[l]      = hout_lds[l];
            ob[l + 64] = hout_lds[l + 64];
            asm volatile("s_waitcnt vmcnt(0)" ::: "memory");   // data acked by L2
            if (l == 0)
                *(volatile unsigned*)&flags[((s << 5) + jj) << 5] = (unsigned)(t + 1);
        }
    }

    // ---- final FC: WG (s, jj<16) -> batch b = 16s+jj (hfin fp32, same XCD) ----
    if (jj < 16) {
        if (wid == 0) {
            int guard = 0;
            for (;;) {
                unsigned fv = *fpoll;
                if (__all((int)(fv >= (unsigned)T_STEPS))) break;
                if (++guard > (1 << 15)) break;
                __builtin_amdgcn_fence(__ATOMIC_ACQUIRE, "agent");
            }
            __builtin_amdgcn_fence(__ATOMIC_ACQUIRE, "agent");
        }
        __syncthreads();
        __builtin_amdgcn_fence(__ATOMIC_ACQUIRE, "agent");  // every wave: L1 clean
        float* hT  = (float*)h_lds;       // 4KB
        float* red = hT + 1024;           // 2KB
        const int b = 16 * s + jj;
        if (tid < 256) {
            f32x4 v = *(const f32x4*)(hfin + (size_t)b * 1024 + tid * 4);
            *(f32x4*)(hT + tid * 4) = v;
        }
        __syncthreads();
        {
            const int o = tid & 127, kq = tid >> 7;
            const float* wr = fc_W + (size_t)o * 1024 + kq * 256;
            const float* hp = hT + kq * 256;
            float p = 0.0f;
            #pragma unroll 8
            for (int i = 0; i < 256; i += 4) {
                f32x4 a = *(const f32x4*)(hp + i);
                f32x4 w = *(const f32x4*)(wr + i);
                p += a[0]*w[0] + a[1]*w[1] + a[2]*w[2] + a[3]*w[3];
            }
            red[kq * 128 + o] = p;
        }
        __syncthreads();
        if (tid < 128) {
            out[(size_t)b * 128 + tid] =
                red[tid] + red[128 + tid] + red[256 + tid] + red[384 + tid] + fc_b[tid];
        }
    }
}

extern "C" void kernel_launch(void* const* d_in, const int* in_sizes, int n_in,
                              void* d_out, int out_size, void* d_ws, size_t ws_size,
                              hipStream_t stream) {
    (void)in_sizes; (void)n_in; (void)out_size; (void)ws_size;
    const float* y_hist = (const float*)d_in[0];
    const float* W_ih   = (const float*)d_in[1];
    const float* W_hh   = (const float*)d_in[2];
    const float* b_ih   = (const float*)d_in[3];
    const float* b_hh   = (const float*)d_in[4];
    const float* fc_W   = (const float*)d_in[5];
    const float* fc_b   = (const float*)d_in[6];
    const float* h0     = (const float*)d_in[7];
    const float* c0     = (const float*)d_in[8];

    // d_ws: hbuf0 (256KB) | hbuf1 (256KB) | hfin (512KB) | flags (32KB, 128B-strided)
    //       | xcnt (128B) | gbar (128B)
    char* ws = (char*)d_ws;
    unsigned long long* hbuf0 = (unsigned long long*)ws;
    unsigned long long* hbuf1 = (unsigned long long*)(ws + (256 << 10));
    float*    hfin  = (float*)(ws + (512 << 10));
    unsigned int* flags = (unsigned int*)(ws + (1024 << 10));
    unsigned int* xcnt  = (unsigned int*)(ws + (1024 << 10) + (32 << 10));
    unsigned int* gbar  = (unsigned int*)(ws + (1024 << 10) + (32 << 10) + 128);

    // xcnt/gbar touched only via MALL-scope atomics -> SDMA memset safe.
    // flags reset in-kernel (stale XCD-L2 lines can't be fixed by SDMA).
    hipMemsetAsync(ws + (1024 << 10) + (32 << 10), 0, 1024, stream);
    // 16KB dynamic LDS pad -> ~81KB/WG -> 1 WG/CU -> 32 WGs per XCD.
    hipLaunchKernelGGL(lstm_persist, dim3(256), dim3(512), 16384, stream,
                       y_hist, W_ih, W_hh, b_ih, b_hh, fc_W, fc_b, h0, c0,
                       (float*)d_out, hbuf0, hbuf1, hfin, flags, xcnt, gbar);
}